// Round 9
// baseline (88.679 us; speedup 1.0000x reference)
//
#include <hip/hip_runtime.h>
#include <math.h>

// Problem constants (static shapes from setup_inputs; all arrays are float32)
#define B_   2
#define T_   8
#define R_   128
#define NP_  32768
#define F_   5
#define S_   32           // num_sample
#define SEG_ 2048         // points per phase-1 segment
#define NSEG (NP_ / SEG_) // 16
#define NBT  (B_ * T_)    // 16
#define NROW (NBT * R_)   // 2048
#define RPB  16           // rois per block (4 per wave, 4 waves)

__device__ __forceinline__ int mbcnt64(unsigned long long m) {
    return __builtin_amdgcn_mbcnt_hi((unsigned)(m >> 32),
           __builtin_amdgcn_mbcnt_lo((unsigned)m, 0u));
}

// ---------- kernel 1: AoS-staged segmented ordered hit collection ----------
// block = 256 (4 waves) on one (bt, seg): stage the 40 KB AoS slab as a packed
// 16 KB xy tile in LDS (register repack), then each wave scans it for 4 rois
// (2 points/lane/ds_read_b128 -> 8 point-roi evals per read). Per-row
// constants (pow + ulp-walk threshold T = max{x : sqrtf(x) <= radius};
// bit-identical selection) computed by lanes 0-3, broadcast via shuffle.
__global__ __launch_bounds__(256) void phase1_collect(
    const float* __restrict__ points,    // [bt, Np, 5]
    const float* __restrict__ rois,      // [bt, R, 9]
    int* __restrict__ counts,            // [row, NSEG]   (row = bt*R + r)
    unsigned short* __restrict__ hitidx) // [row, NSEG, S_]
{
    __shared__ float4 tile[SEG_ / 2];    // 16 KB: 1024 point-pairs

    const int blk = blockIdx.x;                 // (bt*NSEG + seg)*(R_/RPB) + rg
    const int rg  = blk % (R_ / RPB);
    const int bs  = blk / (R_ / RPB);
    const int seg = bs % NSEG;
    const int bt  = bs / NSEG;
    const int tid  = threadIdx.x;
    const int w    = tid >> 6;
    const int lane = tid & 63;

    // ---- stage AoS -> packed xy LDS tile: 512 groups of 4 pts (5 float4 each) ----
    const float4* src = (const float4*)(points + (size_t)bt * NP_ * F_)
                        + (size_t)seg * (SEG_ * F_ / 4);
    #pragma unroll
    for (int i = 0; i < 2; ++i) {
        const int g = tid + i * 256;            // group of 4 points
        const float4* s5 = src + (size_t)g * 5;
        const float4 a = s5[0], bq = s5[1], c = s5[2], d = s5[3], e = s5[4];
        tile[g * 2]     = make_float4(a.x, a.y, bq.y, bq.z);   // pts 4g, 4g+1
        tile[g * 2 + 1] = make_float4(c.z, c.w, d.w, e.x);     // pts 4g+2, 4g+3
    }

    // ---- per-wave roi constants: lane k (k<4) computes row0+k, broadcast ----
    const int row0 = bt * R_ + rg * RPB + w * 4;
    float vcx = 0.0f, vcy = 0.0f, vT = 0.0f;
    if (lane < 4) {
        const int row = row0 + lane;
        const int t   = bt % T_;
        const float* roi = rois + (size_t)row * 9;
        const float cx = roi[0], cy = roi[1];
        const float hx = roi[3] * 0.5f, hy = roi[4] * 0.5f;
        const float vx = roi[7], vy = roi[8];
        const float speed  = sqrtf(vx * vx + vy * vy);
        const float base_g = 1.05f * (1.0f + speed);
        const float expo   = (float)t / 5.0f;
        const float gamma  = fminf((float)pow((double)base_g, (double)expo), 2.5f);
        const float radius = sqrtf(hx * hx + hy * hy) * gamma;
        // ulp-walk: largest float T with sqrtf(T) <= radius
        unsigned ut = __float_as_uint(radius * radius);
        while (sqrtf(__uint_as_float(ut)) > radius) --ut;
        while (sqrtf(__uint_as_float(ut + 1u)) <= radius) ++ut;
        vcx = cx; vcy = cy; vT = __uint_as_float(ut);
    }
    float cxs[4], cys[4], Ts[4];
    #pragma unroll
    for (int k = 0; k < 4; ++k) {
        cxs[k] = __shfl(vcx, k); cys[k] = __shfl(vcy, k); Ts[k] = __shfl(vT, k);
    }
    unsigned short* hs[4];
    int sels[4] = {0, 0, 0, 0};
    #pragma unroll
    for (int k = 0; k < 4; ++k)
        hs[k] = hitidx + ((size_t)(row0 + k) * NSEG + seg) * S_;

    __syncthreads();

    const int ibase = seg * SEG_;
    #pragma unroll 2
    for (int it = 0; it < SEG_ / 128; ++it) {   // 16 iterations, 2 pts/lane
        const float4 q = tile[it * 64 + lane];  // points idx0, idx0+1
        const int idx0 = ibase + (it * 64 + lane) * 2;

        // strict numpy rounding: sub, mul, mul, add separately rounded (no fma)
        #pragma unroll
        for (int k = 0; k < 4; ++k) {
            const float ax = __fsub_rn(q.x, cxs[k]), ay = __fsub_rn(q.y, cys[k]);
            const float bx = __fsub_rn(q.z, cxs[k]), by = __fsub_rn(q.w, cys[k]);
            const float d2a = __fadd_rn(__fmul_rn(ax, ax), __fmul_rn(ay, ay));
            const float d2b = __fadd_rn(__fmul_rn(bx, bx), __fmul_rn(by, by));
            const bool p0 = (d2a <= Ts[k]), p1 = (d2b <= Ts[k]);
            const unsigned long long m0 = __ballot(p0), m1 = __ballot(p1);
            if (m0 | m1) {
                const int base = sels[k] + mbcnt64(m0) + mbcnt64(m1);
                if (p0 && base < S_) hs[k][base] = (unsigned short)idx0;
                if (p1) { const int s = base + (p0 ? 1 : 0);
                          if (s < S_) hs[k][s] = (unsigned short)(idx0 + 1); }
                sels[k] += __popcll(m0) + __popcll(m1);
            }
        }
    }
    if (lane == 0) {
        #pragma unroll
        for (int k = 0; k < 4; ++k)
            counts[(size_t)(row0 + k) * NSEG + seg] = (sels[k] < S_) ? sels[k] : S_;
    }
}

// ---------- kernel 2: prefix + gather + zero-fill ----------
// one thread per (row, slot): 65536 threads.
__global__ __launch_bounds__(256) void phase2_gather(
    const float* __restrict__ points,          // [bt, Np, 5]
    const int* __restrict__ counts,            // [row, NSEG]
    const unsigned short* __restrict__ hitidx, // [row, NSEG, S_]
    float* __restrict__ out)                   // [B, R, T*S, 5]
{
    const int tid  = blockIdx.x * blockDim.x + threadIdx.x;
    const int slot = tid & (S_ - 1);
    const int row  = tid >> 5;                 // S_ == 32
    if (row >= NROW) return;
    const int r  = row % R_;
    const int bt = row / R_;
    const int t  = bt % T_;
    const int b  = bt / T_;

    const int4* cp = (const int4*)(counts + (size_t)row * NSEG);
    const int4 q0 = cp[0], q1 = cp[1], q2 = cp[2], q3 = cp[3];
    const int cs[16] = {q0.x,q0.y,q0.z,q0.w, q1.x,q1.y,q1.z,q1.w,
                        q2.x,q2.y,q2.z,q2.w, q3.x,q3.y,q3.z,q3.w};
    int seg = -1, local = 0, acc = 0;
    #pragma unroll
    for (int s = 0; s < NSEG; ++s) {
        const int na = acc + cs[s];
        if (seg < 0 && slot < na) { seg = s; local = slot - acc; }
        acc = na;
    }
    const int total = (acc < S_) ? acc : S_;

    float* o = out + (((((size_t)b * R_ + r) * T_ + t) * S_) + slot) * F_;
    if (slot < total) {
        const int pi = hitidx[((size_t)row * NSEG + seg) * S_ + local];
        const float* p = points + ((size_t)bt * NP_ + pi) * F_;
        o[0] = p[0]; o[1] = p[1]; o[2] = p[2]; o[3] = p[3]; o[4] = p[4];
    } else {
        o[0] = 0.0f; o[1] = 0.0f; o[2] = 0.0f; o[3] = 0.0f; o[4] = 0.0f;
    }
}

extern "C" void kernel_launch(void* const* d_in, const int* in_sizes, int n_in,
                              void* d_out, int out_size, void* d_ws, size_t ws_size,
                              hipStream_t stream) {
    const float* points = (const float*)d_in[0];
    const float* rois   = (const float*)d_in[1];
    float* out = (float*)d_out;

    // workspace layout (~2.2 MB)
    char* ws = (char*)d_ws;
    int* counts            = (int*)ws;                       //   131,072 B
    unsigned short* hitidx = (unsigned short*)(ws + 131072); // 2,097,152 B

    // 1) AoS-staged ordered hit collection: 16 bt x 16 seg x 8 roi-groups
    phase1_collect<<<NBT * NSEG * (R_ / RPB), 256, 0, stream>>>(points, rois, counts, hitidx);

    // 2) prefix + gather + zero-fill: one thread per (row, slot)
    phase2_gather<<<(NROW * S_) / 256, 256, 0, stream>>>(points, counts, hitidx, out);
}

// Round 10
// 86.303 us; speedup vs baseline: 1.0275x; 1.0275x over previous
//
#include <hip/hip_runtime.h>
#include <math.h>

// Problem constants (static shapes from setup_inputs; all arrays are float32)
#define B_   2
#define T_   8
#define R_   128
#define NP_  32768
#define F_   5
#define S_   32           // num_sample
#define SEG_ 2048         // points per phase-1 segment
#define NSEG (NP_ / SEG_) // 16
#define NBT  (B_ * T_)    // 16
#define NROW (NBT * R_)   // 2048
#define RPB  16           // rois per block (4 per wave, 4 waves)

__device__ __forceinline__ int mbcnt64(unsigned long long m) {
    return __builtin_amdgcn_mbcnt_hi((unsigned)(m >> 32),
           __builtin_amdgcn_mbcnt_lo((unsigned)m, 0u));
}

// ---------- kernel 1: vectorized AoS->SoA xy transpose + per-row constant prep ----------
// (byte-identical to the round-5 passing version)
// T = max{ x : sqrtf(x) <= radius } makes the phase-1 predicate sqrt-free yet
// bit-identical (sqrtf monotone + correctly rounded).
__global__ __launch_bounds__(256) void xy_transpose_prep(
    const float* __restrict__ points,  // [bt, Np, 5]
    const float* __restrict__ rois,    // [bt, R, 9]
    float2* __restrict__ xy,           // [bt, Np]
    float4* __restrict__ rowc)         // [row] = {cx, cy, T, 0}
{
    const int j = blockIdx.x * blockDim.x + threadIdx.x;
    if (j < NBT * NP_ / 4) {
        const float4* src = (const float4*)points + (size_t)j * 5;
        const float4 a = src[0], b = src[1], c = src[2], d = src[3], e = src[4];
        float4* dst = (float4*)xy + (size_t)j * 2;
        dst[0] = make_float4(a.x, a.y, b.y, b.z);   // pts 4j, 4j+1
        dst[1] = make_float4(c.z, c.w, d.w, e.x);   // pts 4j+2, 4j+3
    }
    if (j < NROW) {
        const int row = j;                 // row = bt*R + r
        const int bt  = row / R_;
        const int t   = bt % T_;
        const float* roi = rois + (size_t)row * 9;
        const float cx = roi[0], cy = roi[1];
        const float hx = roi[3] * 0.5f, hy = roi[4] * 0.5f;
        const float vx = roi[7], vy = roi[8];
        const float speed  = sqrtf(vx * vx + vy * vy);
        const float base_g = 1.05f * (1.0f + speed);
        const float expo   = (float)t / 5.0f;
        const float gamma  = fminf((float)pow((double)base_g, (double)expo), 2.5f);
        const float radius = sqrtf(hx * hx + hy * hy) * gamma;
        // ulp-walk: largest float T with sqrtf(T) <= radius
        unsigned ut = __float_as_uint(radius * radius);
        while (sqrtf(__uint_as_float(ut)) > radius) --ut;
        while (sqrtf(__uint_as_float(ut + 1u)) <= radius) ++ut;
        rowc[row] = make_float4(cx, cy, __uint_as_float(ut), 0.0f);
    }
}

// ---------- kernel 2: LDS-staged segmented ordered hit collection ----------
// block = 256 (4 waves) on one (bt, seg): stage the packed 16 KB xy tile into
// LDS with coalesced float4 loads (R5-style), then each wave scans it for 4
// rois (2 points/lane/ds_read_b128 -> 8 point-roi evals per read, R9-verified
// inner loop).
__global__ __launch_bounds__(256) void phase1_collect(
    const float2* __restrict__ xy,       // [bt, Np]
    const float4* __restrict__ rowc,     // [row]
    int* __restrict__ counts,            // [row, NSEG]   (row = bt*R + r)
    unsigned short* __restrict__ hitidx) // [row, NSEG, S_]
{
    __shared__ float4 tile[SEG_ / 2];    // 16 KB: 1024 point-pairs

    const int blk = blockIdx.x;                 // (bt*NSEG + seg)*(R_/RPB) + rg
    const int rg  = blk % (R_ / RPB);
    const int bs  = blk / (R_ / RPB);
    const int seg = bs % NSEG;
    const int bt  = bs / NSEG;
    const int tid  = threadIdx.x;
    const int w    = tid >> 6;
    const int lane = tid & 63;

    // cooperative stage: 1024 float4 / 256 threads = 4 each (fully coalesced)
    const float4* src = (const float4*)(xy + (size_t)bt * NP_ + (size_t)seg * SEG_);
    #pragma unroll
    for (int i = 0; i < 4; ++i)
        tile[i * 256 + tid] = src[i * 256 + tid];

    // per-wave roi constants for 4 rois
    const int row0 = bt * R_ + rg * RPB + w * 4;
    float cxs[4], cys[4], Ts[4];
    unsigned short* hs[4];
    int sels[4] = {0, 0, 0, 0};
    #pragma unroll
    for (int k = 0; k < 4; ++k) {
        const float4 rc = rowc[row0 + k];
        cxs[k] = rc.x; cys[k] = rc.y; Ts[k] = rc.z;
        hs[k] = hitidx + ((size_t)(row0 + k) * NSEG + seg) * S_;
    }
    __syncthreads();

    const int ibase = seg * SEG_;
    #pragma unroll 2
    for (int it = 0; it < SEG_ / 128; ++it) {   // 16 iterations, 2 pts/lane
        const float4 q = tile[it * 64 + lane];  // points idx0, idx0+1
        const int idx0 = ibase + (it * 64 + lane) * 2;

        // strict numpy rounding: sub, mul, mul, add separately rounded (no fma)
        #pragma unroll
        for (int k = 0; k < 4; ++k) {
            const float ax = __fsub_rn(q.x, cxs[k]), ay = __fsub_rn(q.y, cys[k]);
            const float bx = __fsub_rn(q.z, cxs[k]), by = __fsub_rn(q.w, cys[k]);
            const float d2a = __fadd_rn(__fmul_rn(ax, ax), __fmul_rn(ay, ay));
            const float d2b = __fadd_rn(__fmul_rn(bx, bx), __fmul_rn(by, by));
            const bool p0 = (d2a <= Ts[k]), p1 = (d2b <= Ts[k]);
            const unsigned long long m0 = __ballot(p0), m1 = __ballot(p1);
            if (m0 | m1) {
                const int base = sels[k] + mbcnt64(m0) + mbcnt64(m1);
                if (p0 && base < S_) hs[k][base] = (unsigned short)idx0;
                if (p1) { const int s = base + (p0 ? 1 : 0);
                          if (s < S_) hs[k][s] = (unsigned short)(idx0 + 1); }
                sels[k] += __popcll(m0) + __popcll(m1);
            }
        }
    }
    if (lane == 0) {
        #pragma unroll
        for (int k = 0; k < 4; ++k)
            counts[(size_t)(row0 + k) * NSEG + seg] = (sels[k] < S_) ? sels[k] : S_;
    }
}

// ---------- kernel 3: prefix + gather + zero-fill ----------
// one thread per (row, slot): 65536 threads.
__global__ __launch_bounds__(256) void phase2_gather(
    const float* __restrict__ points,          // [bt, Np, 5]
    const int* __restrict__ counts,            // [row, NSEG]
    const unsigned short* __restrict__ hitidx, // [row, NSEG, S_]
    float* __restrict__ out)                   // [B, R, T*S, 5]
{
    const int tid  = blockIdx.x * blockDim.x + threadIdx.x;
    const int slot = tid & (S_ - 1);
    const int row  = tid >> 5;                 // S_ == 32
    if (row >= NROW) return;
    const int r  = row % R_;
    const int bt = row / R_;
    const int t  = bt % T_;
    const int b  = bt / T_;

    const int4* cp = (const int4*)(counts + (size_t)row * NSEG);
    const int4 q0 = cp[0], q1 = cp[1], q2 = cp[2], q3 = cp[3];
    const int cs[16] = {q0.x,q0.y,q0.z,q0.w, q1.x,q1.y,q1.z,q1.w,
                        q2.x,q2.y,q2.z,q2.w, q3.x,q3.y,q3.z,q3.w};
    int seg = -1, local = 0, acc = 0;
    #pragma unroll
    for (int s = 0; s < NSEG; ++s) {
        const int na = acc + cs[s];
        if (seg < 0 && slot < na) { seg = s; local = slot - acc; }
        acc = na;
    }
    const int total = (acc < S_) ? acc : S_;

    float* o = out + (((((size_t)b * R_ + r) * T_ + t) * S_) + slot) * F_;
    if (slot < total) {
        const int pi = hitidx[((size_t)row * NSEG + seg) * S_ + local];
        const float* p = points + ((size_t)bt * NP_ + pi) * F_;
        o[0] = p[0]; o[1] = p[1]; o[2] = p[2]; o[3] = p[3]; o[4] = p[4];
    } else {
        o[0] = 0.0f; o[1] = 0.0f; o[2] = 0.0f; o[3] = 0.0f; o[4] = 0.0f;
    }
}

extern "C" void kernel_launch(void* const* d_in, const int* in_sizes, int n_in,
                              void* d_out, int out_size, void* d_ws, size_t ws_size,
                              hipStream_t stream) {
    const float* points = (const float*)d_in[0];
    const float* rois   = (const float*)d_in[1];
    float* out = (float*)d_out;

    // workspace layout (~6.4 MB)
    char* ws = (char*)d_ws;
    float2* xy             = (float2*)ws;                                   // 4,194,304 B
    int* counts            = (int*)(ws + 4194304);                          //   131,072 B
    unsigned short* hitidx = (unsigned short*)(ws + 4194304 + 131072);      // 2,097,152 B
    float4* rowc           = (float4*)(ws + 4194304 + 131072 + 2097152);    //    32,768 B

    // 1) vectorized transpose + per-row constants (fused)
    xy_transpose_prep<<<(NBT * NP_ / 4 + 255) / 256, 256, 0, stream>>>(points, rois, xy, rowc);

    // 2) LDS-staged ordered hit collection: 16 bt x 16 seg x 8 roi-groups
    phase1_collect<<<NBT * NSEG * (R_ / RPB), 256, 0, stream>>>(xy, rowc, counts, hitidx);

    // 3) prefix + gather + zero-fill: one thread per (row, slot)
    phase2_gather<<<(NROW * S_) / 256, 256, 0, stream>>>(points, counts, hitidx, out);
}